// Round 11
// baseline (62.021 us; speedup 1.0000x reference)
//
#include <hip/hip_runtime.h>

#define NPIX (512*512)
#define NIMG 32
#define CTR 255.5f
#define NCH 32            // chunks (blocks) per image
#define NTHR 256
#define PXCH (NPIX/NCH)   // 8192 px per chunk
#define QCH  (PXCH/4)     // 2048 float4 quads per chunk
#define PLANE 1024        // NIMG*NCH

__device__ __forceinline__ double wredd(double v) {
#pragma unroll
    for (int off = 32; off; off >>= 1) v += __shfl_down(v, off, 64);
    return v;
}

__device__ __forceinline__ double aload(const double* p) {
    return __hip_atomic_load(p, __ATOMIC_RELAXED, __HIP_MEMORY_SCOPE_AGENT);
}
__device__ __forceinline__ void astore(double* p, double v) {
    __hip_atomic_store(p, v, __ATOMIC_RELAXED, __HIP_MEMORY_SCOPE_AGENT);
}

__global__ __launch_bounds__(64) void initk(int* ctr) {
    ctr[threadIdx.x] = 0;   // ctr1[32] + ctr2[32]
}

// One worker kernel. Phase A: single cold pass over x, gray staged in LDS,
// 11 raw-moment partials published via relaxed atomic stores (coherence
// point). Handoff: atomicAdd(ctr1) ordered by __syncthreads' vmcnt drain;
// spin uses RELAXED loads only (no acquire -> no L2 invalidates). Phase B:
// |g-mean| from LDS gray. Last arriver finalizes.
__global__ __launch_bounds__(NTHR) void fused(const float* __restrict__ x,
                                              double* __restrict__ p1,
                                              double* __restrict__ p2,
                                              int* __restrict__ ctr,
                                              float* __restrict__ out) {
    __shared__ float4 gbuf[QCH];         // 32 KB gray cache
    __shared__ double lds[4][11];
    __shared__ double bmean;
    __shared__ int is_last;

    int img = blockIdx.x >> 5;
    int chunk = blockIdx.x & (NCH - 1);
    size_t cb = (size_t)chunk * PXCH;
    const float* xr = x + (size_t)img * 3 * NPIX;
    int lane = threadIdx.x & 63, wv = threadIdx.x >> 6;
    int* ctr1 = ctr;
    int* ctr2 = ctr + NIMG;

    // ---- Phase A ----
    double D[11];
#pragma unroll
    for (int a = 0; a < 11; ++a) D[a] = 0.0;

#pragma unroll
    for (int it = 0; it < 2; ++it) {
        float4 Rv[4], Gv[4], Bv[4];
#pragma unroll
        for (int j = 0; j < 4; ++j) {
            int q = (it * 4 + j) * NTHR + threadIdx.x;
            size_t off = cb + (size_t)q * 4;
            Rv[j] = *(const float4*)(xr + off);
            Gv[j] = *(const float4*)(xr + NPIX + off);
            Bv[j] = *(const float4*)(xr + 2 * NPIX + off);
        }
        float A[11];
#pragma unroll
        for (int a = 0; a < 11; ++a) A[a] = 0.0f;
#pragma unroll
        for (int j = 0; j < 4; ++j) {
            int q = (it * 4 + j) * NTHR + threadIdx.x;
            int off = (int)cb + q * 4;
            float gv[4];
            gv[0] = 0.299f * Rv[j].x + 0.587f * Gv[j].x + 0.114f * Bv[j].x;
            gv[1] = 0.299f * Rv[j].y + 0.587f * Gv[j].y + 0.114f * Bv[j].y;
            gv[2] = 0.299f * Rv[j].z + 0.587f * Gv[j].z + 0.114f * Bv[j].z;
            gv[3] = 0.299f * Rv[j].w + 0.587f * Gv[j].w + 0.114f * Bv[j].w;
            gbuf[q] = make_float4(gv[0], gv[1], gv[2], gv[3]);
            float v = (float)(off >> 9) - CTR;
            float v2 = v * v, v3 = v2 * v;
            float u0 = (float)(off & 511) - CTR;
#pragma unroll
            for (int u = 0; u < 4; ++u) {
                float gg = gv[u];
                float uu = u0 + (float)u;
                float t1 = gg * uu, t2 = t1 * uu, t3 = t2 * uu;
                A[0] += gg;
                A[1] += gg * gg;
                A[2] += t1;
                A[3] += gg * v;
                A[4] += t2;
                A[5] += t1 * v;
                A[6] += gg * v2;
                A[7] += t3;
                A[8] += t2 * v;
                A[9] += t1 * v2;
                A[10] += gg * v3;
            }
        }
#pragma unroll
        for (int a = 0; a < 11; ++a) D[a] += (double)A[a];
    }

#pragma unroll
    for (int a = 0; a < 11; ++a) {
        double s = wredd(D[a]);
        if (lane == 0) lds[wv][a] = s;
    }
    __syncthreads();
    if (threadIdx.x < 11)
        astore(&p1[(size_t)threadIdx.x * PLANE + (size_t)img * NCH + chunk],
               lds[0][threadIdx.x] + lds[1][threadIdx.x] + lds[2][threadIdx.x] + lds[3][threadIdx.x]);
    __syncthreads();   // vmcnt(0): p1 stores complete before ctr1 add

    // ---- handoff + spin (relaxed only) ----
    if (threadIdx.x == 0) {
        atomicAdd(&ctr1[img], 1);
        while (__hip_atomic_load(&ctr1[img], __ATOMIC_RELAXED,
                                 __HIP_MEMORY_SCOPE_AGENT) < NCH)
            __builtin_amdgcn_s_sleep(8);
    }
    __syncthreads();

    // ---- mean ----
    if (wv == 0) {
        double sg = (lane < NCH) ? aload(&p1[(size_t)img * NCH + lane]) : 0.0;
        sg = wredd(sg);
        if (lane == 0) bmean = sg / (double)NPIX;
    }
    __syncthreads();
    float mean = (float)bmean;

    // ---- Phase B: |g - mean| from LDS gray ----
    double Dsa = 0.0, Dsax = 0.0, Dsay = 0.0;
#pragma unroll
    for (int it = 0; it < 2; ++it) {
        float sa = 0.0f, sax = 0.0f, say = 0.0f;
#pragma unroll
        for (int j = 0; j < 4; ++j) {
            int q = (it * 4 + j) * NTHR + threadIdx.x;
            int off = (int)cb + q * 4;
            float4 g4 = gbuf[q];
            float gv[4] = {g4.x, g4.y, g4.z, g4.w};
            float v = (float)(off >> 9) - CTR;
            float u0 = (float)(off & 511) - CTR;
#pragma unroll
            for (int u = 0; u < 4; ++u) {
                float a = fabsf(gv[u] - mean);
                sa += a;
                sax += a * (u0 + (float)u);
                say += a * v;
            }
        }
        Dsa += (double)sa; Dsax += (double)sax; Dsay += (double)say;
    }
    {
        double acc[3] = {Dsa, Dsax, Dsay};
#pragma unroll
        for (int a = 0; a < 3; ++a) {
            double s = wredd(acc[a]);
            if (lane == 0) lds[wv][a] = s;
        }
        __syncthreads();
        if (threadIdx.x < 3)
            astore(&p2[(size_t)threadIdx.x * PLANE + (size_t)img * NCH + chunk],
                   lds[0][threadIdx.x] + lds[1][threadIdx.x] + lds[2][threadIdx.x] + lds[3][threadIdx.x]);
    }
    __syncthreads();   // vmcnt(0): p2 stores complete before ctr2 add

    if (threadIdx.x == 0)
        is_last = (atomicAdd(&ctr2[img], 1) == NCH - 1);
    __syncthreads();
    if (!is_last || threadIdx.x >= 64) return;

    // ---- finalize (one wave of the last-arriving block) ----
    double M[11], B[3];
#pragma unroll
    for (int a = 0; a < 11; ++a)
        M[a] = (lane < NCH) ? aload(&p1[(size_t)a * PLANE + (size_t)img * NCH + lane]) : 0.0;
#pragma unroll
    for (int a = 0; a < 3; ++a)
        B[a] = (lane < NCH) ? aload(&p2[(size_t)a * PLANE + (size_t)img * NCH + lane]) : 0.0;
#pragma unroll
    for (int a = 0; a < 11; ++a) M[a] = wredd(M[a]);
#pragma unroll
    for (int a = 0; a < 3; ++a) B[a] = wredd(B[a]);

    if (lane == 0) {
        const double N = (double)NPIX;
        double G00 = M[0], Sg2 = M[1];
        double G10 = M[2], G01 = M[3], G20 = M[4], G11 = M[5], G02 = M[6];
        double G30 = M[7], G21 = M[8], G12 = M[9], G03 = M[10];
        double A0 = B[0], Ax = B[1], Ay = B[2];

        double mean2 = G00 / N;
        double var = Sg2 / N - mean2 * mean2;
        if (var < 0.0) var = 0.0;
        double inv_std = 1.0 / (sqrt(var) + 1e-8);

        double s_chk = A0 * inv_std;
        double dx, dy;  // cx-255.5, cy-255.5
        if (s_chk < 1e-8) { dx = 0.5; dy = 0.5; }
        else { dx = Ax / A0; dy = Ay / A0; }

        double S2 = 512.0 * (512.0 * 512.0 - 1.0) / 12.0;
        double P20 = S2 * 512.0, P02 = S2 * 512.0;

        double W00 = G00 - mean2 * N;
        double W10 = G10, W01 = G01;
        double W20 = G20 - mean2 * P20;
        double W11 = G11;
        double W02 = G02 - mean2 * P02;
        double W30 = G30, W21 = G21, W12 = G12, W03 = G03;

        double N00 = W00;
        double N10 = W10 - dx * W00;
        double N01 = W01 - dy * W00;
        double N20 = W20 - 2.0 * dx * W10 + dx * dx * W00;
        double N11 = W11 - dx * W01 - dy * W10 + dx * dy * W00;
        double N02 = W02 - 2.0 * dy * W01 + dy * dy * W00;
        double N30 = W30 - 3.0 * dx * W20 + 3.0 * dx * dx * W10 - dx * dx * dx * W00;
        double N21 = W21 - dy * W20 - 2.0 * dx * W11 + 2.0 * dx * dy * W10
                   + dx * dx * W01 - dx * dx * dy * W00;
        double N12 = W12 - dx * W02 - 2.0 * dy * W11 + 2.0 * dx * dy * W01
                   + dy * dy * W10 - dx * dy * dy * W00;
        double N03 = W03 - 3.0 * dy * W02 + 3.0 * dy * dy * W01 - dy * dy * dy * W00;

        double cx = (double)CTR + dx, cy = (double)CTR + dy;
        double mdx = fmax(cx, 511.0 - cx), mdy = fmax(cy, 511.0 - cy);
        double max_r = sqrt(mdx * mdx + mdy * mdy) + 1e-8;
        double imr = 1.0 / max_r;
        double im1 = inv_std * imr, im2 = im1 * imr, im3 = im2 * imr;
        double inv_denom = 1.0 / (max_r * max_r + 1e-8);

        double S0 = N00 * inv_std;
        double R2 = (N20 + N02) * im2;
        double C1 = N10 * im1, S1 = N01 * im1;
        double C2 = (N20 - N02) * im2, Sm2 = 2.0 * N11 * im2;
        double C3 = (N30 - 3.0 * N12) * im3, Sm3 = (3.0 * N21 - N03) * im3;
        double C31 = (N30 + N12) * im3, S31 = (N21 + N03) * im3;

        double f0 = fabs(S0) * inv_denom;
        double f1 = sqrt(C1 * C1 + S1 * S1) * inv_denom;
        double f3 = sqrt(C2 * C2 + Sm2 * Sm2) * inv_denom;
        double f4 = fabs(2.0 * R2 - S0) * inv_denom;
        double f6 = sqrt(C3 * C3 + Sm3 * Sm3) * inv_denom;
        double a31r = 3.0 * C31 - 2.0 * C1, a31i = 3.0 * S31 - 2.0 * S1;
        double f7 = sqrt(a31r * a31r + a31i * a31i) * inv_denom;

        float* o = out + (size_t)img * 20;
        o[0] = (float)f0;
        o[1] = (float)f1; o[2] = (float)f1;
        o[3] = (float)f3; o[4] = (float)f4; o[5] = (float)f3;
        o[6] = (float)f6; o[7] = (float)f7; o[8] = (float)f7; o[9] = (float)f6;
        for (int k = 10; k < 20; ++k) o[k] = 0.0f;
    }
}

extern "C" void kernel_launch(void* const* d_in, const int* in_sizes, int n_in,
                              void* d_out, int out_size, void* d_ws, size_t ws_size,
                              hipStream_t stream) {
    const float* x = (const float*)d_in[0];
    float* out = (float*)d_out;

    int* ctr = (int*)d_ws;                               // 64 ints
    double* p1 = (double*)((char*)d_ws + 1024);          // 11*1024 doubles
    double* p2 = p1 + (size_t)11 * PLANE;                // 3*1024 doubles

    initk<<<1, 64, 0, stream>>>(ctr);
    fused<<<NIMG * NCH, NTHR, 0, stream>>>(x, p1, p2, ctr, out);
}

// Round 12
// 37.454 us; speedup vs baseline: 1.6559x; 1.6559x over previous
//
#include <hip/hip_runtime.h>
#include <hip/hip_fp16.h>

#define NPIX (512*512)
#define NIMG 32
#define CTR 255.5f
#define NCH 64            // chunks (blocks) per image
#define NTHR 256
#define NP1 12

__device__ __forceinline__ double wredd(double v) {
#pragma unroll
    for (int off = 32; off; off >>= 1) v += __shfl_down(v, off, 64);
    return v;
}

// K1: raw moments over x (one cold 100 MB pass) + fp16 gray cache write.
__global__ __launch_bounds__(NTHR) void k1(const float* __restrict__ x,
                                           double* __restrict__ p1,
                                           __half* __restrict__ gray) {
    int img = blockIdx.x >> 6;
    int chunk = blockIdx.x & (NCH - 1);
    size_t cb = (size_t)chunk * (NPIX / NCH);   // 4096 px per chunk
    const float* xr = x + (size_t)img * 3 * NPIX;
    __half* gh = gray + (size_t)img * NPIX;

    float4 Rv[4], Gv[4], Bv[4];
#pragma unroll
    for (int j = 0; j < 4; ++j) {
        size_t off = cb + ((size_t)j * NTHR + threadIdx.x) * 4;
        Rv[j] = *(const float4*)(xr + off);
        Gv[j] = *(const float4*)(xr + NPIX + off);
        Bv[j] = *(const float4*)(xr + 2 * NPIX + off);
    }

    float A[11];
#pragma unroll
    for (int a = 0; a < 11; ++a) A[a] = 0.0f;

#pragma unroll
    for (int j = 0; j < 4; ++j) {
        size_t off = cb + ((size_t)j * NTHR + threadIdx.x) * 4;
        float gv[4];
        gv[0] = 0.299f * Rv[j].x + 0.587f * Gv[j].x + 0.114f * Bv[j].x;
        gv[1] = 0.299f * Rv[j].y + 0.587f * Gv[j].y + 0.114f * Bv[j].y;
        gv[2] = 0.299f * Rv[j].z + 0.587f * Gv[j].z + 0.114f * Bv[j].z;
        gv[3] = 0.299f * Rv[j].w + 0.587f * Gv[j].w + 0.114f * Bv[j].w;

        __half2 h01 = __floats2half2_rn(gv[0], gv[1]);
        __half2 h23 = __floats2half2_rn(gv[2], gv[3]);
        uint2 pk;
        pk.x = *(unsigned int*)&h01;
        pk.y = *(unsigned int*)&h23;
        *(uint2*)(gh + off) = pk;

        float v = (float)(int)(off >> 9) - CTR;
        float v2 = v * v, v3 = v2 * v;
        float u0 = (float)(int)(off & 511) - CTR;
#pragma unroll
        for (int u = 0; u < 4; ++u) {
            float gg = gv[u];
            float uu = u0 + (float)u;
            float t1 = gg * uu, t2 = t1 * uu, t3 = t2 * uu;
            A[0] += gg;
            A[1] += gg * gg;
            A[2] += t1;
            A[3] += gg * v;
            A[4] += t2;
            A[5] += t1 * v;
            A[6] += gg * v2;
            A[7] += t3;
            A[8] += t2 * v;
            A[9] += t1 * v2;
            A[10] += gg * v3;
        }
    }

    __shared__ double lds[4][11];
    int lane = threadIdx.x & 63, wv = threadIdx.x >> 6;
#pragma unroll
    for (int a = 0; a < 11; ++a) {
        double s = wredd((double)A[a]);
        if (lane == 0) lds[wv][a] = s;
    }
    __syncthreads();
    if (threadIdx.x < 11)
        p1[((size_t)img * NCH + chunk) * NP1 + threadIdx.x] =
            lds[0][threadIdx.x] + lds[1][threadIdx.x] + lds[2][threadIdx.x] + lds[3][threadIdx.x];
}

// K2: |g - mean| sums reading the small fp16 gray (17 MB instead of 100 MB).
__global__ __launch_bounds__(NTHR) void k2(const __half* __restrict__ gray,
                                           const double* __restrict__ p1,
                                           double* __restrict__ p2) {
    int img = blockIdx.x >> 6;
    int chunk = blockIdx.x & (NCH - 1);
    size_t cb = (size_t)chunk * (NPIX / NCH);
    const __half* gh = gray + (size_t)img * NPIX;
    int lane = threadIdx.x & 63, wv = threadIdx.x >> 6;

    uint4 raw[2];
#pragma unroll
    for (int j = 0; j < 2; ++j) {
        size_t p = cb + ((size_t)j * NTHR + threadIdx.x) * 8;
        raw[j] = *(const uint4*)(gh + p);
    }

    __shared__ double bmean;
    if (wv == 0) {
        double sg = p1[((size_t)img * NCH + lane) * NP1 + 0];
        sg = wredd(sg);
        if (lane == 0) bmean = sg / (double)NPIX;
    }
    __syncthreads();
    float mean = (float)bmean;

    float sa = 0.0f, sax = 0.0f, say = 0.0f;
#pragma unroll
    for (int j = 0; j < 2; ++j) {
        size_t p = cb + ((size_t)j * NTHR + threadIdx.x) * 8;
        float v = (float)(int)(p >> 9) - CTR;
        float u0 = (float)(int)(p & 511) - CTR;
        unsigned int w[4] = {raw[j].x, raw[j].y, raw[j].z, raw[j].w};
#pragma unroll
        for (int h = 0; h < 4; ++h) {
            __half2 hh = *(__half2*)&w[h];
            float2 f2 = __half22float2(hh);
            float a0 = fabsf(f2.x - mean);
            float a1 = fabsf(f2.y - mean);
            sa += a0 + a1;
            sax += a0 * (u0 + (float)(2 * h)) + a1 * (u0 + (float)(2 * h + 1));
            say += (a0 + a1) * v;
        }
    }
    __shared__ double lds2[4][3];
    {
        float acc[3] = {sa, sax, say};
#pragma unroll
        for (int a = 0; a < 3; ++a) {
            double s = wredd((double)acc[a]);
            if (lane == 0) lds2[wv][a] = s;
        }
    }
    __syncthreads();
    if (threadIdx.x < 3)
        p2[((size_t)img * NCH + chunk) * 3 + threadIdx.x] =
            lds2[0][threadIdx.x] + lds2[1][threadIdx.x] + lds2[2][threadIdx.x] + lds2[3][threadIdx.x];
}

// K3: finalize, one wave per image (64 lanes = 64 chunks).
__global__ __launch_bounds__(64) void k3f(const double* __restrict__ p1,
                                          const double* __restrict__ p2,
                                          float* __restrict__ out) {
    int img = blockIdx.x;
    int lane = threadIdx.x;
    size_t b = (size_t)img * NCH + lane;
    double M[11], B[3];
#pragma unroll
    for (int a = 0; a < 11; ++a) M[a] = p1[b * NP1 + a];
#pragma unroll
    for (int a = 0; a < 3; ++a) B[a] = p2[b * 3 + a];
#pragma unroll
    for (int a = 0; a < 11; ++a) M[a] = wredd(M[a]);
#pragma unroll
    for (int a = 0; a < 3; ++a) B[a] = wredd(B[a]);

    if (lane == 0) {
        const double N = (double)NPIX;
        double G00 = M[0], Sg2 = M[1];
        double G10 = M[2], G01 = M[3], G20 = M[4], G11 = M[5], G02 = M[6];
        double G30 = M[7], G21 = M[8], G12 = M[9], G03 = M[10];
        double A0 = B[0], Ax = B[1], Ay = B[2];

        double mean2 = G00 / N;
        double var = Sg2 / N - mean2 * mean2;
        if (var < 0.0) var = 0.0;
        double inv_std = 1.0 / (sqrt(var) + 1e-8);

        double s_chk = A0 * inv_std;
        double dx, dy;  // cx-255.5, cy-255.5
        if (s_chk < 1e-8) { dx = 0.5; dy = 0.5; }
        else { dx = Ax / A0; dy = Ay / A0; }

        double S2 = 512.0 * (512.0 * 512.0 - 1.0) / 12.0;
        double P20 = S2 * 512.0, P02 = S2 * 512.0;

        double W00 = G00 - mean2 * N;
        double W10 = G10, W01 = G01;
        double W20 = G20 - mean2 * P20;
        double W11 = G11;
        double W02 = G02 - mean2 * P02;
        double W30 = G30, W21 = G21, W12 = G12, W03 = G03;

        double N00 = W00;
        double N10 = W10 - dx * W00;
        double N01 = W01 - dy * W00;
        double N20 = W20 - 2.0 * dx * W10 + dx * dx * W00;
        double N11 = W11 - dx * W01 - dy * W10 + dx * dy * W00;
        double N02 = W02 - 2.0 * dy * W01 + dy * dy * W00;
        double N30 = W30 - 3.0 * dx * W20 + 3.0 * dx * dx * W10 - dx * dx * dx * W00;
        double N21 = W21 - dy * W20 - 2.0 * dx * W11 + 2.0 * dx * dy * W10
                   + dx * dx * W01 - dx * dx * dy * W00;
        double N12 = W12 - dx * W02 - 2.0 * dy * W11 + 2.0 * dx * dy * W01
                   + dy * dy * W10 - dx * dy * dy * W00;
        double N03 = W03 - 3.0 * dy * W02 + 3.0 * dy * dy * W01 - dy * dy * dy * W00;

        double cx = (double)CTR + dx, cy = (double)CTR + dy;
        double mdx = fmax(cx, 511.0 - cx), mdy = fmax(cy, 511.0 - cy);
        double max_r = sqrt(mdx * mdx + mdy * mdy) + 1e-8;
        double imr = 1.0 / max_r;
        double im1 = inv_std * imr, im2 = im1 * imr, im3 = im2 * imr;
        double inv_denom = 1.0 / (max_r * max_r + 1e-8);

        double S0 = N00 * inv_std;
        double R2 = (N20 + N02) * im2;
        double C1 = N10 * im1, S1 = N01 * im1;
        double C2 = (N20 - N02) * im2, Sm2 = 2.0 * N11 * im2;
        double C3 = (N30 - 3.0 * N12) * im3, Sm3 = (3.0 * N21 - N03) * im3;
        double C31 = (N30 + N12) * im3, S31 = (N21 + N03) * im3;

        double f0 = fabs(S0) * inv_denom;
        double f1 = sqrt(C1 * C1 + S1 * S1) * inv_denom;
        double f3 = sqrt(C2 * C2 + Sm2 * Sm2) * inv_denom;
        double f4 = fabs(2.0 * R2 - S0) * inv_denom;
        double f6 = sqrt(C3 * C3 + Sm3 * Sm3) * inv_denom;
        double a31r = 3.0 * C31 - 2.0 * C1, a31i = 3.0 * S31 - 2.0 * S1;
        double f7 = sqrt(a31r * a31r + a31i * a31i) * inv_denom;

        float* o = out + (size_t)img * 20;
        o[0] = (float)f0;
        o[1] = (float)f1; o[2] = (float)f1;
        o[3] = (float)f3; o[4] = (float)f4; o[5] = (float)f3;
        o[6] = (float)f6; o[7] = (float)f7; o[8] = (float)f7; o[9] = (float)f6;
        for (int k = 10; k < 20; ++k) o[k] = 0.0f;
    }
}

extern "C" void kernel_launch(void* const* d_in, const int* in_sizes, int n_in,
                              void* d_out, int out_size, void* d_ws, size_t ws_size,
                              hipStream_t stream) {
    const float* x = (const float*)d_in[0];
    float* out = (float*)d_out;

    double* p1 = (double*)d_ws;                           // 2048*12 doubles
    double* p2 = p1 + (size_t)NIMG * NCH * NP1;           // 2048*3 doubles
    size_t base = ((size_t)NIMG * NCH * (NP1 + 3) * sizeof(double) + 255) & ~(size_t)255;
    __half* gray = (__half*)((char*)d_ws + base);         // 16.8 MB fp16 cache

    dim3 grid(NIMG * NCH);
    k1<<<grid, NTHR, 0, stream>>>(x, p1, gray);
    k2<<<grid, NTHR, 0, stream>>>(gray, p1, p2);
    k3f<<<NIMG, 64, 0, stream>>>(p1, p2, out);
}

// Round 13
// 36.918 us; speedup vs baseline: 1.6800x; 1.0145x over previous
//
#include <hip/hip_runtime.h>

#define NPIX (512*512)
#define NIMG 32
#define CTR 255.5f
#define NCH 64            // chunks (blocks) per image
#define NTHR 256
#define NP1 12
#define GSCL 32.0f
#define GINV 0.03125f

__device__ __forceinline__ double wredd(double v) {
#pragma unroll
    for (int off = 32; off; off >>= 1) v += __shfl_down(v, off, 64);
    return v;
}

// K1: raw moments over x (one cold 100 MB pass) + int8 gray cache write.
__global__ __launch_bounds__(NTHR) void k1(const float* __restrict__ x,
                                           double* __restrict__ p1,
                                           char* __restrict__ gray) {
    int img = blockIdx.x >> 6;
    int chunk = blockIdx.x & (NCH - 1);
    size_t cb = (size_t)chunk * (NPIX / NCH);   // 4096 px per chunk
    const float* xr = x + (size_t)img * 3 * NPIX;
    char* g8 = gray + (size_t)img * NPIX;

    float4 Rv[4], Gv[4], Bv[4];
#pragma unroll
    for (int j = 0; j < 4; ++j) {
        size_t off = cb + ((size_t)j * NTHR + threadIdx.x) * 4;
        Rv[j] = *(const float4*)(xr + off);
        Gv[j] = *(const float4*)(xr + NPIX + off);
        Bv[j] = *(const float4*)(xr + 2 * NPIX + off);
    }

    float A[11];
#pragma unroll
    for (int a = 0; a < 11; ++a) A[a] = 0.0f;

#pragma unroll
    for (int j = 0; j < 4; ++j) {
        size_t off = cb + ((size_t)j * NTHR + threadIdx.x) * 4;
        float gv[4];
        gv[0] = 0.299f * Rv[j].x + 0.587f * Gv[j].x + 0.114f * Bv[j].x;
        gv[1] = 0.299f * Rv[j].y + 0.587f * Gv[j].y + 0.114f * Bv[j].y;
        gv[2] = 0.299f * Rv[j].z + 0.587f * Gv[j].z + 0.114f * Bv[j].z;
        gv[3] = 0.299f * Rv[j].w + 0.587f * Gv[j].w + 0.114f * Bv[j].w;

        unsigned int pk = 0;
#pragma unroll
        for (int u = 0; u < 4; ++u) {
            int q = (int)rintf(gv[u] * GSCL);
            q = q > 127 ? 127 : (q < -127 ? -127 : q);
            pk |= ((unsigned int)(q & 0xff)) << (8 * u);
        }
        *(unsigned int*)(g8 + off) = pk;

        float v = (float)(int)(off >> 9) - CTR;
        float v2 = v * v, v3 = v2 * v;
        float u0 = (float)(int)(off & 511) - CTR;
#pragma unroll
        for (int u = 0; u < 4; ++u) {
            float gg = gv[u];
            float uu = u0 + (float)u;
            float t1 = gg * uu, t2 = t1 * uu, t3 = t2 * uu;
            A[0] += gg;
            A[1] += gg * gg;
            A[2] += t1;
            A[3] += gg * v;
            A[4] += t2;
            A[5] += t1 * v;
            A[6] += gg * v2;
            A[7] += t3;
            A[8] += t2 * v;
            A[9] += t1 * v2;
            A[10] += gg * v3;
        }
    }

    __shared__ double lds[4][11];
    int lane = threadIdx.x & 63, wv = threadIdx.x >> 6;
#pragma unroll
    for (int a = 0; a < 11; ++a) {
        double s = wredd((double)A[a]);
        if (lane == 0) lds[wv][a] = s;
    }
    __syncthreads();
    if (threadIdx.x < 11)
        p1[((size_t)img * NCH + chunk) * NP1 + threadIdx.x] =
            lds[0][threadIdx.x] + lds[1][threadIdx.x] + lds[2][threadIdx.x] + lds[3][threadIdx.x];
}

// K2: |g - mean| sums from int8 gray (8.4 MB, partially L2-hot).
// One uint4 load per thread = 16 consecutive px (never crosses a row).
__global__ __launch_bounds__(NTHR) void k2(const char* __restrict__ gray,
                                           const double* __restrict__ p1,
                                           double* __restrict__ p2) {
    int img = blockIdx.x >> 6;
    int chunk = blockIdx.x & (NCH - 1);
    size_t cb = (size_t)chunk * (NPIX / NCH);
    const char* g8 = gray + (size_t)img * NPIX;
    int lane = threadIdx.x & 63, wv = threadIdx.x >> 6;

    size_t p = cb + (size_t)threadIdx.x * 16;
    uint4 raw = *(const uint4*)(g8 + p);

    __shared__ double bmean;
    if (wv == 0) {
        double sg = p1[((size_t)img * NCH + lane) * NP1 + 0];
        sg = wredd(sg);
        if (lane == 0) bmean = sg / (double)NPIX;
    }
    __syncthreads();
    float mean = (float)bmean;

    float v = (float)(int)(p >> 9) - CTR;
    float u0 = (float)(int)(p & 511) - CTR;
    float sa = 0.0f, sax = 0.0f;
    unsigned int w[4] = {raw.x, raw.y, raw.z, raw.w};
#pragma unroll
    for (int d = 0; d < 4; ++d) {
#pragma unroll
        for (int b = 0; b < 4; ++b) {
            float g = (float)(signed char)((w[d] >> (8 * b)) & 0xff) * GINV;
            float a = fabsf(g - mean);
            sa += a;
            sax += a * (u0 + (float)(4 * d + b));
        }
    }
    float say = sa * v;   // v constant across the 16 px

    __shared__ double lds2[4][3];
    {
        float acc[3] = {sa, sax, say};
#pragma unroll
        for (int a = 0; a < 3; ++a) {
            double s = wredd((double)acc[a]);
            if (lane == 0) lds2[wv][a] = s;
        }
    }
    __syncthreads();
    if (threadIdx.x < 3)
        p2[((size_t)img * NCH + chunk) * 3 + threadIdx.x] =
            lds2[0][threadIdx.x] + lds2[1][threadIdx.x] + lds2[2][threadIdx.x] + lds2[3][threadIdx.x];
}

// K3: finalize, one wave per image (64 lanes = 64 chunks).
__global__ __launch_bounds__(64) void k3f(const double* __restrict__ p1,
                                          const double* __restrict__ p2,
                                          float* __restrict__ out) {
    int img = blockIdx.x;
    int lane = threadIdx.x;
    size_t b = (size_t)img * NCH + lane;
    double M[11], B[3];
#pragma unroll
    for (int a = 0; a < 11; ++a) M[a] = p1[b * NP1 + a];
#pragma unroll
    for (int a = 0; a < 3; ++a) B[a] = p2[b * 3 + a];
#pragma unroll
    for (int a = 0; a < 11; ++a) M[a] = wredd(M[a]);
#pragma unroll
    for (int a = 0; a < 3; ++a) B[a] = wredd(B[a]);

    if (lane == 0) {
        const double N = (double)NPIX;
        double G00 = M[0], Sg2 = M[1];
        double G10 = M[2], G01 = M[3], G20 = M[4], G11 = M[5], G02 = M[6];
        double G30 = M[7], G21 = M[8], G12 = M[9], G03 = M[10];
        double A0 = B[0], Ax = B[1], Ay = B[2];

        double mean2 = G00 / N;
        double var = Sg2 / N - mean2 * mean2;
        if (var < 0.0) var = 0.0;
        double inv_std = 1.0 / (sqrt(var) + 1e-8);

        double s_chk = A0 * inv_std;
        double dx, dy;  // cx-255.5, cy-255.5
        if (s_chk < 1e-8) { dx = 0.5; dy = 0.5; }
        else { dx = Ax / A0; dy = Ay / A0; }

        double S2 = 512.0 * (512.0 * 512.0 - 1.0) / 12.0;
        double P20 = S2 * 512.0, P02 = S2 * 512.0;

        double W00 = G00 - mean2 * N;
        double W10 = G10, W01 = G01;
        double W20 = G20 - mean2 * P20;
        double W11 = G11;
        double W02 = G02 - mean2 * P02;
        double W30 = G30, W21 = G21, W12 = G12, W03 = G03;

        double N00 = W00;
        double N10 = W10 - dx * W00;
        double N01 = W01 - dy * W00;
        double N20 = W20 - 2.0 * dx * W10 + dx * dx * W00;
        double N11 = W11 - dx * W01 - dy * W10 + dx * dy * W00;
        double N02 = W02 - 2.0 * dy * W01 + dy * dy * W00;
        double N30 = W30 - 3.0 * dx * W20 + 3.0 * dx * dx * W10 - dx * dx * dx * W00;
        double N21 = W21 - dy * W20 - 2.0 * dx * W11 + 2.0 * dx * dy * W10
                   + dx * dx * W01 - dx * dx * dy * W00;
        double N12 = W12 - dx * W02 - 2.0 * dy * W11 + 2.0 * dx * dy * W01
                   + dy * dy * W10 - dx * dy * dy * W00;
        double N03 = W03 - 3.0 * dy * W02 + 3.0 * dy * dy * W01 - dy * dy * dy * W00;

        double cx = (double)CTR + dx, cy = (double)CTR + dy;
        double mdx = fmax(cx, 511.0 - cx), mdy = fmax(cy, 511.0 - cy);
        double max_r = sqrt(mdx * mdx + mdy * mdy) + 1e-8;
        double imr = 1.0 / max_r;
        double im1 = inv_std * imr, im2 = im1 * imr, im3 = im2 * imr;
        double inv_denom = 1.0 / (max_r * max_r + 1e-8);

        double S0 = N00 * inv_std;
        double R2 = (N20 + N02) * im2;
        double C1 = N10 * im1, S1 = N01 * im1;
        double C2 = (N20 - N02) * im2, Sm2 = 2.0 * N11 * im2;
        double C3 = (N30 - 3.0 * N12) * im3, Sm3 = (3.0 * N21 - N03) * im3;
        double C31 = (N30 + N12) * im3, S31 = (N21 + N03) * im3;

        double f0 = fabs(S0) * inv_denom;
        double f1 = sqrt(C1 * C1 + S1 * S1) * inv_denom;
        double f3 = sqrt(C2 * C2 + Sm2 * Sm2) * inv_denom;
        double f4 = fabs(2.0 * R2 - S0) * inv_denom;
        double f6 = sqrt(C3 * C3 + Sm3 * Sm3) * inv_denom;
        double a31r = 3.0 * C31 - 2.0 * C1, a31i = 3.0 * S31 - 2.0 * S1;
        double f7 = sqrt(a31r * a31r + a31i * a31i) * inv_denom;

        float* o = out + (size_t)img * 20;
        o[0] = (float)f0;
        o[1] = (float)f1; o[2] = (float)f1;
        o[3] = (float)f3; o[4] = (float)f4; o[5] = (float)f3;
        o[6] = (float)f6; o[7] = (float)f7; o[8] = (float)f7; o[9] = (float)f6;
        for (int k = 10; k < 20; ++k) o[k] = 0.0f;
    }
}

extern "C" void kernel_launch(void* const* d_in, const int* in_sizes, int n_in,
                              void* d_out, int out_size, void* d_ws, size_t ws_size,
                              hipStream_t stream) {
    const float* x = (const float*)d_in[0];
    float* out = (float*)d_out;

    double* p1 = (double*)d_ws;                           // 2048*12 doubles
    double* p2 = p1 + (size_t)NIMG * NCH * NP1;           // 2048*3 doubles
    size_t base = ((size_t)NIMG * NCH * (NP1 + 3) * sizeof(double) + 255) & ~(size_t)255;
    char* gray = (char*)d_ws + base;                      // 8.4 MB int8 cache

    dim3 grid(NIMG * NCH);
    k1<<<grid, NTHR, 0, stream>>>(x, p1, gray);
    k2<<<grid, NTHR, 0, stream>>>(gray, p1, p2);
    k3f<<<NIMG, 64, 0, stream>>>(p1, p2, out);
}